// Round 1
// baseline (185.129 us; speedup 1.0000x reference)
//
#include <hip/hip_runtime.h>

// ComboSumModule: six independent sum-over-axis-1 reductions (f32).
// Shapes: (2048,128,64) (2048,32,32) (2048,64,64) (2048,16,48)
//         (2048,200,32) (2048,8,8). Outputs concatenated flat.
//
// R6 theory: R4/R5 were latency/scheduling-bound, not BW-bound (4.7 B/cyc/CU
// = ~4 loads in flight per CU vs 48KB that should be). Dead time came from
// block-level structure: 1140 one-shot 1024-thread blocks, 2/CU resident,
// ~2.2 dispatch generations, 16-wave __syncthreads convoy + lead-wave-only
// LDS combine + re-dispatch gaps. R6 removes all of it:
//   - rows split across LANE GROUPS inside one wave (shfl_xor combine);
//     no LDS, no __syncthreads, waves fully independent.
//   - 816 blocks x 256 thr (3264 waves) -- entire grid co-resident
//     (3.2 blk/CU, 0 LDS, VGPR<=128 via launch_bounds(256,4)): one
//     generation, zero launch gaps.
//   - explicit va/vb double-buffer with sched_barrier(0) fences: 8-16
//     1KB loads in flight per wave continuously (vmcnt(8) waits, no drain).
// Predicted: dur 58 -> ~28-35us, VGPR -> ~96-128, VALUBusy ~3-4%,
// occupancy ~40% (not the constraint), LDS 0.

__device__ __forceinline__ float4 f4add(float4 a, float4 b) {
  return make_float4(a.x + b.x, a.y + b.y, a.z + b.z, a.w + b.w);
}

template <int STRIDE4, int B>
__device__ __forceinline__ void load_batch(float4 (&v)[B],
                                           const float4* __restrict__ q) {
#pragma unroll
  for (int i = 0; i < B; ++i) v[i] = q[(size_t)i * STRIDE4];
}

template <int B>
__device__ __forceinline__ void add_batch(const float4 (&v)[B], float4& a0,
                                          float4& a1, float4& a2, float4& a3) {
#pragma unroll
  for (int i = 0; i < B; ++i) {
    if ((i & 3) == 0) a0 = f4add(a0, v[i]);
    else if ((i & 3) == 1) a1 = f4add(a1, v[i]);
    else if ((i & 3) == 2) a2 = f4add(a2, v[i]);
    else a3 = f4add(a3, v[i]);
  }
}

// Sum ROWS rows (stride STRIDE4 float4s) starting at p, for this lane's
// float4 column. Double-buffered batches of 8: loads of batch k issue
// before adds of batch k-1 (sched_barrier(0) pins the order), so the wave
// always has ~8-16 loads outstanding and waits only vmcnt(B), never drain.
template <int ROWS, int STRIDE4>
__device__ __forceinline__ float4 col_sum(const float4* __restrict__ p) {
  constexpr int B = (ROWS >= 8) ? 8 : ROWS;
  constexpr int NB = ROWS / B;
  constexpr int TAIL = ROWS - NB * B;

  float4 va[B], vb[B];
  float4 a0 = make_float4(0.f, 0.f, 0.f, 0.f);
  float4 a1 = a0, a2 = a0, a3 = a0;

  load_batch<STRIDE4>(va, p);
  __builtin_amdgcn_sched_barrier(0);

#pragma unroll
  for (int k = 1; k < NB; ++k) {
    const float4* q = p + (size_t)(k * B) * STRIDE4;
    if (k & 1) {
      load_batch<STRIDE4>(vb, q);
      __builtin_amdgcn_sched_barrier(0);
      add_batch(va, a0, a1, a2, a3);
    } else {
      load_batch<STRIDE4>(va, q);
      __builtin_amdgcn_sched_barrier(0);
      add_batch(vb, a0, a1, a2, a3);
    }
    __builtin_amdgcn_sched_barrier(0);
  }

  if constexpr (TAIL > 0) {
    float4 vt[TAIL];
    load_batch<STRIDE4>(vt, p + (size_t)(NB * B) * STRIDE4);
    __builtin_amdgcn_sched_barrier(0);
    if constexpr (((NB - 1) & 1) != 0) add_batch(vb, a0, a1, a2, a3);
    else add_batch(va, a0, a1, a2, a3);
    add_batch(vt, a0, a1, a2, a3);
  } else {
    if constexpr (((NB - 1) & 1) != 0) add_batch(vb, a0, a1, a2, a3);
    else add_batch(va, a0, a1, a2, a3);
  }
  return f4add(f4add(a0, a1), f4add(a2, a3));
}

// One wave handles one task: 64/SPLIT float4 output units, with SPLIT lane
// groups each summing M/SPLIT rows; shfl_xor combines groups (no LDS).
template <int M, int N, int SPLIT>
__device__ __forceinline__ void tensor_sum(const float* __restrict__ xp,
                                           float4* __restrict__ out4,
                                           int task, int lane) {
  constexpr int N4 = N / 4;
  constexpr int UN = 64 / SPLIT;   // units per wave
  constexpr int ROWS = M / SPLIT;  // rows per lane group
  const int ul = lane & (UN - 1);
  const int part = lane / UN;  // which row chunk (0..SPLIT-1)
  const int u = task * UN + ul;
  const int b = u / N4;  // const divisor -> magic-mul
  const int n4 = u - b * N4;
  const float4* p = reinterpret_cast<const float4*>(xp) +
                    (size_t)b * (M * N4) + (size_t)(part * ROWS) * N4 + n4;

  float4 r = col_sum<ROWS, N4>(p);

  if constexpr (SPLIT == 4) {
    r.x += __shfl_xor(r.x, 16);
    r.y += __shfl_xor(r.y, 16);
    r.z += __shfl_xor(r.z, 16);
    r.w += __shfl_xor(r.w, 16);
  }
  if constexpr (SPLIT >= 2) {
    r.x += __shfl_xor(r.x, 32);
    r.y += __shfl_xor(r.y, 32);
    r.z += __shfl_xor(r.z, 32);
    r.w += __shfl_xor(r.w, 32);
  }
  if (part == 0) out4[u] = r;
}

// Wave-task map (heavy first; all region sizes divisible by 4 waves so the
// region branch is block-uniform):
//   wid [   0,1024): x0 M=128 N=64 SPLIT=2 (64 rows/lane-half)
//   wid [1024,2048): x4 M=200 N=32 SPLIT=4 (50 rows/lane-quad)
//   wid [2048,2560): x2 M= 64 N=64 SPLIT=1
//   wid [2560,2816): x1 M= 32 N=32 SPLIT=1
//   wid [2816,3200): x3 M= 16 N=48 SPLIT=1
//   wid [3200,3264): x5 M=  8 N= 8 SPLIT=1
// Output float4 bases: x0 0, x1 32768, x2 49152, x3 81920, x4 106496,
// x5 122880 (outputs concatenated in input order).
__global__ __launch_bounds__(256, 4) void ComboSumModule_25314537242674_kernel(
    const float* __restrict__ x0, const float* __restrict__ x1,
    const float* __restrict__ x2, const float* __restrict__ x3,
    const float* __restrict__ x4, const float* __restrict__ x5,
    float* __restrict__ out) {
  const int lane = threadIdx.x & 63;
  const int wid = (blockIdx.x << 2) | (threadIdx.x >> 6);
  float4* out4 = reinterpret_cast<float4*>(out);

  if (wid < 1024) {
    tensor_sum<128, 64, 2>(x0, out4 + 0, wid, lane);
  } else if (wid < 2048) {
    tensor_sum<200, 32, 4>(x4, out4 + 106496, wid - 1024, lane);
  } else if (wid < 2560) {
    tensor_sum<64, 64, 1>(x2, out4 + 49152, wid - 2048, lane);
  } else if (wid < 2816) {
    tensor_sum<32, 32, 1>(x1, out4 + 32768, wid - 2560, lane);
  } else if (wid < 3200) {
    tensor_sum<16, 48, 1>(x3, out4 + 81920, wid - 2816, lane);
  } else {
    tensor_sum<8, 8, 1>(x5, out4 + 122880, wid - 3200, lane);
  }
}

extern "C" void kernel_launch(void* const* d_in, const int* in_sizes, int n_in,
                              void* d_out, int out_size, void* d_ws,
                              size_t ws_size, hipStream_t stream) {
  const float* x0 = (const float*)d_in[0];
  const float* x1 = (const float*)d_in[1];
  const float* x2 = (const float*)d_in[2];
  const float* x3 = (const float*)d_in[3];
  const float* x4 = (const float*)d_in[4];
  const float* x5 = (const float*)d_in[5];
  // d_in[6] is the python scalar dim=1; reduction axis baked in.
  float* out = (float*)d_out;

  ComboSumModule_25314537242674_kernel<<<816, 256, 0, stream>>>(x0, x1, x2, x3,
                                                                x4, x5, out);
}